// Round 5
// baseline (459.822 us; speedup 1.0000x reference)
//
#include <hip/hip_runtime.h>
#include <hip/hip_cooperative_groups.h>
#include <cstdint>

namespace cg = cooperative_groups;

// ---------------- types ----------------
typedef __bf16 bf16x8 __attribute__((ext_vector_type(8)));
typedef __bf16 bf16x4 __attribute__((ext_vector_type(4)));
typedef float  f32x4  __attribute__((ext_vector_type(4)));

#define N_PTS 8192
#define FDIM  64
#define NF    (N_PTS * FDIM)

struct Params {
    const float *x, *w1, *b1, *w2, *b2, *w3, *b3;
    const float *wa1, *ba1, *wa2, *ba2, *wb1, *bb1, *wb2, *bb2;
    __bf16 *xe, *uT;
    float *Dp, *colp, *sqp, *outp, *out;
};

__device__ __forceinline__ float ftanh(float x) {
    float e = __expf(2.f * x);
    return 1.f - 2.f / (e + 1.f);
}

// One cooperative kernel; 512 blocks x 256 threads = 2 blocks/CU co-resident.
// LDS: single 36.9 KB buffer overlaid per phase (73.7 KB/CU at 2 blk/CU).
__global__ __launch_bounds__(256, 2) void k_mega(Params p)
{
    __shared__ __bf16 smem[18432];             // 36864 B
    const int tid = threadIdx.x, bid = blockIdx.x;
    const int wave = tid >> 6, lane = tid & 63, c = lane & 15, q = lane >> 4;
    cg::grid_group grid = cg::this_grid();

    // ================= phase 1: encode MLP -> xe (bf16) =================
    {
#pragma unroll
        for (int k = 0; k < 4; k++) {
            int idx = bid * 256 + tid + k * 131072;
            float2 pt = ((const float2*)p.x)[idx];
            float h1[4], h2[4];
#pragma unroll
            for (int o = 0; o < 4; o++)
                h1[o] = ftanh(pt.x * p.w1[o] + pt.y * p.w1[4 + o] + p.b1[o]);
#pragma unroll
            for (int o = 0; o < 4; o++) {
                float s = p.b2[o];
#pragma unroll
                for (int i = 0; i < 4; i++) s += h1[i] * p.w2[i * 4 + o];
                h2[o] = ftanh(s);
            }
            float s3 = p.b3[0];
#pragma unroll
            for (int i = 0; i < 4; i++) s3 += h2[i] * p.w3[i];
            p.xe[idx] = (__bf16)ftanh(s3);
        }
    }
    grid.sync();

    // ================= phase 2: D partials (pass1) =================
    // 512 blocks = 128 j-tiles x 4 i-slices of 2048. 16 Dp partial slices.
    {
        __bf16* sI = smem;                     // [128][72]
        const int j0 = (bid >> 2) * 64;
        const int ibase = (bid & 3) * 2048;

        bf16x8 Bf[4][2];
#pragma unroll
        for (int jt = 0; jt < 4; jt++)
#pragma unroll
            for (int kc = 0; kc < 2; kc++)
                Bf[jt][kc] = *(const bf16x8*)(p.xe + (j0 + 16 * jt + c) * 64 + kc * 32 + q * 8);

        float es[4] = {0.f, 0.f, 0.f, 0.f};
        for (int ic = 0; ic < 16; ic++) {
            __syncthreads();
#pragma unroll
            for (int k = 0; k < 4; k++) {
                int seg = tid + k * 256; int r = seg >> 3, c8 = seg & 7;
                *(uint4*)(sI + r * 72 + c8 * 8) =
                    *(const uint4*)(p.xe + (ibase + ic * 128 + r) * 64 + c8 * 8);
            }
            __syncthreads();
#pragma unroll
            for (int g = 0; g < 2; g++) {
                bf16x8 a0 = *(const bf16x8*)(sI + (32 * wave + 16 * g + c) * 72 + q * 8);
                bf16x8 a1 = *(const bf16x8*)(sI + (32 * wave + 16 * g + c) * 72 + 32 + q * 8);
#pragma unroll
                for (int jt = 0; jt < 4; jt++) {
                    f32x4 s = {0.f, 0.f, 0.f, 0.f};
                    s = __builtin_amdgcn_mfma_f32_16x16x32_bf16(a0, Bf[jt][0], s, 0, 0, 0);
                    s = __builtin_amdgcn_mfma_f32_16x16x32_bf16(a1, Bf[jt][1], s, 0, 0, 0);
                    es[jt] += __expf(s.x) + __expf(s.y) + __expf(s.z) + __expf(s.w);
                }
            }
        }
#pragma unroll
        for (int jt = 0; jt < 4; jt++) {
            es[jt] += __shfl_xor(es[jt], 16);
            es[jt] += __shfl_xor(es[jt], 32);
        }
        if (q == 0) {
            float* d = p.Dp + ((bid & 3) * 4 + wave) * N_PTS + j0;
#pragma unroll
            for (int jt = 0; jt < 4; jt++) d[16 * jt + c] = es[jt];
        }
    }
    grid.sync();

    // ================= phase 3: build uT[f][j] = xe[j][f]/D[j] =================
    // 128 active blocks of 64 j each.
    if (bid < 128) {
        __bf16* T = smem;                      // [64][72]
        const int j0 = bid * 64;
        const int r = tid >> 2, cg4 = tid & 3;
        float dsum = 0.f;
#pragma unroll
        for (int s = 0; s < 16; s++) dsum += p.Dp[s * N_PTS + j0 + r];
        float invd = 1.0f / dsum;
        bf16x8 v0 = *(const bf16x8*)(p.xe + (j0 + r) * 64 + cg4 * 16);
        bf16x8 v1 = *(const bf16x8*)(p.xe + (j0 + r) * 64 + cg4 * 16 + 8);
#pragma unroll
        for (int e = 0; e < 8; e++) {
            T[(cg4 * 16 + e) * 72 + r]     = (__bf16)((float)v0[e] * invd);
            T[(cg4 * 16 + 8 + e) * 72 + r] = (__bf16)((float)v1[e] * invd);
        }
        __syncthreads();
        uint4 w0 = *(uint4*)((char*)T + r * 144 + cg4 * 32);
        uint4 w1 = *(uint4*)((char*)T + r * 144 + cg4 * 32 + 16);
        *(uint4*)(p.uT + r * 8192 + j0 + cg4 * 16)     = w0;
        *(uint4*)(p.uT + r * 8192 + j0 + cg4 * 16 + 8) = w1;
    }
    grid.sync();

    // ================= phase 4: outp[slice] = exp(S_slice) @ u =================
    // 512 blocks = 64 i-tiles of 128 rows x 8 j-slices of 1024.
    {
        __bf16* sJ = smem;                     // [64][72]
        __bf16* sU = smem + 4608;              // [64][72]
        __bf16* sP = smem + 9216;              // [128][72]
        const int ibase = (bid >> 3) * 128;
        const int jbase = (bid & 7) * 1024;

        bf16x8 bst[2][2];
#pragma unroll
        for (int isub = 0; isub < 2; isub++)
#pragma unroll
            for (int kc = 0; kc < 2; kc++)
                bst[isub][kc] = *(const bf16x8*)(
                    p.xe + (ibase + 32 * wave + 16 * isub + c) * 64 + kc * 32 + q * 8);

        f32x4 o[2][4];
#pragma unroll
        for (int g = 0; g < 2; g++)
#pragma unroll
            for (int ft = 0; ft < 4; ft++) o[g][ft] = (f32x4){0.f, 0.f, 0.f, 0.f};

        for (int jc = 0; jc < 16; jc++) {
            const int j0 = jbase + jc * 64;
            __syncthreads();
#pragma unroll
            for (int k = 0; k < 2; k++) {
                int seg = tid + k * 256; int r = seg >> 3, c8 = seg & 7;
                *(uint4*)(sJ + r * 72 + c8 * 8) = *(const uint4*)(p.xe + (j0 + r) * 64 + c8 * 8);
                *(uint4*)(sU + r * 72 + c8 * 8) = *(const uint4*)(p.uT + r * 8192 + j0 + c8 * 8);
            }
            __syncthreads();

            // S-phase: lane -> S[i=ibase+32w+16isub+c][j=j0+16jt+4q+r]
#pragma unroll
            for (int jt = 0; jt < 4; jt++) {
                bf16x8 a0 = *(const bf16x8*)(sJ + (16 * jt + c) * 72 + q * 8);
                bf16x8 a1 = *(const bf16x8*)(sJ + (16 * jt + c) * 72 + 32 + q * 8);
#pragma unroll
                for (int isub = 0; isub < 2; isub++) {
                    f32x4 s = {0.f, 0.f, 0.f, 0.f};
                    s = __builtin_amdgcn_mfma_f32_16x16x32_bf16(a0, bst[isub][0], s, 0, 0, 0);
                    s = __builtin_amdgcn_mfma_f32_16x16x32_bf16(a1, bst[isub][1], s, 0, 0, 0);
                    bf16x4 pv;
                    pv[0] = (__bf16)__expf(s[0]); pv[1] = (__bf16)__expf(s[1]);
                    pv[2] = (__bf16)__expf(s[2]); pv[3] = (__bf16)__expf(s[3]);
                    *(bf16x4*)(sP + (32 * wave + 16 * isub + c) * 72 + 16 * jt + 4 * q) = pv;
                }
            }
            // PV-phase: sP rows 32w..32w+31 wave-private, no barrier needed
#pragma unroll
            for (int kc = 0; kc < 2; kc++) {
                bf16x8 ap0 = *(const bf16x8*)(sP + (32 * wave + c) * 72 + kc * 32 + q * 8);
                bf16x8 ap1 = *(const bf16x8*)(sP + (32 * wave + 16 + c) * 72 + kc * 32 + q * 8);
#pragma unroll
                for (int ft = 0; ft < 4; ft++) {
                    bf16x8 bu = *(const bf16x8*)(sU + (16 * ft + c) * 72 + kc * 32 + q * 8);
                    o[0][ft] = __builtin_amdgcn_mfma_f32_16x16x32_bf16(ap0, bu, o[0][ft], 0, 0, 0);
                    o[1][ft] = __builtin_amdgcn_mfma_f32_16x16x32_bf16(ap1, bu, o[1][ft], 0, 0, 0);
                }
            }
        }
        float* dst = p.outp + (size_t)(bid & 7) * NF;
#pragma unroll
        for (int g = 0; g < 2; g++)
#pragma unroll
            for (int ft = 0; ft < 4; ft++)
#pragma unroll
                for (int r = 0; r < 4; r++)
                    dst[(ibase + 32 * wave + 16 * g + 4 * q + r) * 64 + 16 * ft + c] =
                        o[g][ft][r];
    }
    grid.sync();

    // ================= phase 5: combine slices -> out, col/sq partials ========
    // 512 blocks; thread owns 4 positions at stride 131072 (%64==0 -> fixed col)
    {
        float* svf = (float*)smem;             // [256]
        float* swf = svf + 256;                // [4]
        const int base = bid * 256 + tid;
        float col = 0.f, sq = 0.f;
#pragma unroll
        for (int k = 0; k < 4; k++) {
            int idx = base + k * 131072;
            float acc = 0.f;
#pragma unroll
            for (int s = 0; s < 8; s++) acc += p.outp[(size_t)s * NF + idx];
            p.out[idx] = acc;
            col += acc; sq += acc * acc;
        }
        svf[tid] = col;
#pragma unroll
        for (int m = 32; m; m >>= 1) sq += __shfl_xor(sq, m);
        if ((tid & 63) == 0) swf[tid >> 6] = sq;
        __syncthreads();
        if (tid < 64) {
            float t = svf[tid] + svf[tid + 64] + svf[tid + 128] + svf[tid + 192];
            p.colp[bid * 64 + tid] = t;
        }
        if (tid == 0) p.sqp[bid] = swf[0] + swf[1] + swf[2] + swf[3];
    }
    grid.sync();

    // ================= phase 6: reduce partials, m -> alpha, beta =============
    if (bid == 0 && tid < 64) {
        const int f = tid;
        float colsum = 0.f;
        for (int b = 0; b < 512; b++) colsum += p.colp[b * 64 + f];
        float ss = colsum * colsum;
#pragma unroll
        for (int m = 32; m; m >>= 1) ss += __shfl_xor(ss, m);
        float sq = 0.f;
#pragma unroll
        for (int k = 0; k < 8; k++) sq += p.sqp[f + 64 * k];
#pragma unroll
        for (int m = 32; m; m >>= 1) sq += __shfl_xor(sq, m);
        if (f == 0) {
            const float invN = 1.f / 8192.f;
            float m = 2.f * invN * sq - 2.f * invN * invN * ss;
            float h0 = tanhf(m * p.wa1[0] + p.ba1[0]);
            float h1 = tanhf(m * p.wa1[1] + p.ba1[1]);
            float a  = tanhf(h0 * p.wa2[0] + h1 * p.wa2[1] + p.ba2[0]);
            float g0 = tanhf(m * p.wb1[0] + p.bb1[0]);
            float g1 = tanhf(m * p.wb1[1] + p.bb1[1]);
            float b  = tanhf(g0 * p.wb2[0] + g1 * p.wb2[1] + p.bb2[0]);
            p.out[NF]     = __expf(3.f * a);
            p.out[NF + 1] = __expf(-3.f * b);
        }
    }
}

// ---------------- launcher ----------------------------------------------------
extern "C" void kernel_launch(void* const* d_in, const int* in_sizes, int n_in,
                              void* d_out, int out_size, void* d_ws, size_t ws_size,
                              hipStream_t stream)
{
    char* ws = (char*)d_ws;
    Params prm;
    prm.x   = (const float*)d_in[0];
    prm.w1  = (const float*)d_in[1];  prm.b1  = (const float*)d_in[2];
    prm.w2  = (const float*)d_in[3];  prm.b2  = (const float*)d_in[4];
    prm.w3  = (const float*)d_in[5];  prm.b3  = (const float*)d_in[6];
    prm.wa1 = (const float*)d_in[7];  prm.ba1 = (const float*)d_in[8];
    prm.wa2 = (const float*)d_in[9];  prm.ba2 = (const float*)d_in[10];
    prm.wb1 = (const float*)d_in[11]; prm.bb1 = (const float*)d_in[12];
    prm.wb2 = (const float*)d_in[13]; prm.bb2 = (const float*)d_in[14];
    prm.xe  = (__bf16*)ws;                              // 1 MB
    prm.uT  = (__bf16*)(ws + (1 << 20));                // 1 MB
    prm.Dp  = (float*)(ws + (2 << 20));                 // 16 x 32 KB = 512 KB
    prm.colp = (float*)(ws + (2 << 20) + (512 << 10));  // 128 KB
    prm.sqp  = (float*)(ws + (2 << 20) + (640 << 10));  // 2 KB
    prm.outp = (float*)(ws + (4 << 20));                // 8 x 2 MB = 16 MB
    prm.out  = (float*)d_out;

    void* kargs[] = { (void*)&prm };
    hipLaunchCooperativeKernel((void*)k_mega, dim3(512), dim3(256),
                               kargs, 0, stream);
}

// Round 6
// 205.689 us; speedup vs baseline: 2.2355x; 2.2355x over previous
//
#include <hip/hip_runtime.h>
#include <cstdint>

// ---------------- types ----------------
typedef __bf16 bf16x8 __attribute__((ext_vector_type(8)));
typedef __bf16 bf16x4 __attribute__((ext_vector_type(4)));
typedef float  f32x4  __attribute__((ext_vector_type(4)));

#define N_PTS 8192
#define FDIM  64
#define NF    (N_PTS * FDIM)

__device__ __forceinline__ float ftanh(float x) {
    float e = __expf(2.f * x);
    return 1.f - 2.f / (e + 1.f);
}

// ---------------- kernel 1: per-pair encode MLP -> xe (bf16) ----------------
// Also zeroes the combine ticket (stream order guarantees it precedes combine).
__global__ __launch_bounds__(256) void k_encode(
    const float* __restrict__ x,
    const float* __restrict__ w1, const float* __restrict__ b1,
    const float* __restrict__ w2, const float* __restrict__ b2,
    const float* __restrict__ w3, const float* __restrict__ b3,
    __bf16* __restrict__ xe, int* __restrict__ ctix)
{
    if (blockIdx.x == 0 && threadIdx.x == 0) *ctix = 0;
    int idx = blockIdx.x * 256 + threadIdx.x;   // < NF
    float2 p = ((const float2*)x)[idx];
    float h1[4], h2[4];
#pragma unroll
    for (int o = 0; o < 4; o++)
        h1[o] = ftanh(p.x * w1[o] + p.y * w1[4 + o] + b1[o]);
#pragma unroll
    for (int o = 0; o < 4; o++) {
        float s = b2[o];
#pragma unroll
        for (int i = 0; i < 4; i++) s += h1[i] * w2[i * 4 + o];
        h2[o] = ftanh(s);
    }
    float s3 = b3[0];
#pragma unroll
    for (int i = 0; i < 4; i++) s3 += h2[i] * w3[i];
    xe[idx] = (__bf16)ftanh(s3);
}

// ---------------- kernel 2: D partials -----------------------------------------
// Block owns 64 j (B-frags in registers); i-rows streamed through LDS, split
// across waves. grid (128 j-tiles, 8 i-slices of 1024). 32 Dp partial slices.
__global__ __launch_bounds__(256) void k_pass1(
    const __bf16* __restrict__ xe, float* __restrict__ Dp)
{
    __shared__ __bf16 sI[128 * 72];            // padded stride 72: conflict-free
    const int tid = threadIdx.x;
    const int j0 = blockIdx.x * 64;
    const int ibase = blockIdx.y * 1024;
    const int wave = tid >> 6, lane = tid & 63, c = lane & 15, q = lane >> 4;

    bf16x8 Bf[4][2];
#pragma unroll
    for (int jt = 0; jt < 4; jt++)
#pragma unroll
        for (int kc = 0; kc < 2; kc++)
            Bf[jt][kc] = *(const bf16x8*)(xe + (j0 + 16 * jt + c) * 64 + kc * 32 + q * 8);

    float es[4] = {0.f, 0.f, 0.f, 0.f};
    for (int ic = 0; ic < 8; ic++) {
        __syncthreads();
#pragma unroll
        for (int k = 0; k < 4; k++) {
            int seg = tid + k * 256; int r = seg >> 3, c8 = seg & 7;
            *(uint4*)(sI + r * 72 + c8 * 8) =
                *(const uint4*)(xe + (ibase + ic * 128 + r) * 64 + c8 * 8);
        }
        __syncthreads();
#pragma unroll
        for (int g = 0; g < 2; g++) {
            bf16x8 a0 = *(const bf16x8*)(sI + (32 * wave + 16 * g + c) * 72 + q * 8);
            bf16x8 a1 = *(const bf16x8*)(sI + (32 * wave + 16 * g + c) * 72 + 32 + q * 8);
#pragma unroll
            for (int jt = 0; jt < 4; jt++) {
                f32x4 s = {0.f, 0.f, 0.f, 0.f};
                s = __builtin_amdgcn_mfma_f32_16x16x32_bf16(a0, Bf[jt][0], s, 0, 0, 0);
                s = __builtin_amdgcn_mfma_f32_16x16x32_bf16(a1, Bf[jt][1], s, 0, 0, 0);
                es[jt] += __expf(s.x) + __expf(s.y) + __expf(s.z) + __expf(s.w);
            }
        }
    }
#pragma unroll
    for (int jt = 0; jt < 4; jt++) {
        es[jt] += __shfl_xor(es[jt], 16);
        es[jt] += __shfl_xor(es[jt], 32);
    }
    if (q == 0) {
        float* d = Dp + (blockIdx.y * 4 + wave) * N_PTS + j0;
#pragma unroll
        for (int jt = 0; jt < 4; jt++) d[16 * jt + c] = es[jt];
    }
}

// ---------------- kernel 3: uT[f][j] = bf16(xe[j][f] / sum(Dp[:,j])) ----------
__global__ __launch_bounds__(256) void k_build_u(
    const __bf16* __restrict__ xe, const float* __restrict__ Dp,
    __bf16* __restrict__ uT)
{
    __shared__ __bf16 T[64 * 72];
    const int tid = threadIdx.x;
    const int j0 = blockIdx.x * 64;
    const int r = tid >> 2, cg = tid & 3;
    float dsum = 0.f;
#pragma unroll
    for (int s = 0; s < 32; s++) dsum += Dp[s * N_PTS + j0 + r];
    float invd = 1.0f / dsum;
    bf16x8 v0 = *(const bf16x8*)(xe + (j0 + r) * 64 + cg * 16);
    bf16x8 v1 = *(const bf16x8*)(xe + (j0 + r) * 64 + cg * 16 + 8);
#pragma unroll
    for (int e = 0; e < 8; e++) {
        T[(cg * 16 + e) * 72 + r]     = (__bf16)((float)v0[e] * invd);
        T[(cg * 16 + 8 + e) * 72 + r] = (__bf16)((float)v1[e] * invd);
    }
    __syncthreads();
    uint4 w0 = *(uint4*)((char*)T + r * 144 + cg * 32);
    uint4 w1 = *(uint4*)((char*)T + r * 144 + cg * 32 + 16);
    *(uint4*)(uT + r * 8192 + j0 + cg * 16)     = w0;
    *(uint4*)(uT + r * 8192 + j0 + cg * 16 + 8) = w1;
}

// ---------------- kernel 4: outp[slice] = exp(S_slice) @ u  (MFMA) ------------
// grid (64 i-tiles of 128, 8 j-slices of 1024); 4 waves; wave owns 32 i-rows.
// 8 outp slices (16 MB total). Proven body (R5 phase 4), re-gridded.
__global__ __launch_bounds__(256, 2) void k_pass2(
    const __bf16* __restrict__ xe, const __bf16* __restrict__ uT,
    float* __restrict__ outp)
{
    __shared__ __bf16 sJ[64 * 72];       //  9.2 KB
    __shared__ __bf16 sU[64 * 72];       //  9.2 KB
    __shared__ __bf16 sP[128 * 72];      // 18.4 KB -> 36.9 KB total, 2+ blk/CU
    const int tid = threadIdx.x;
    const int ibase = blockIdx.x * 128;
    const int jbase = blockIdx.y * 1024;
    const int wave = tid >> 6, lane = tid & 63, c = lane & 15, q = lane >> 4;

    bf16x8 bst[2][2];
#pragma unroll
    for (int isub = 0; isub < 2; isub++)
#pragma unroll
        for (int kc = 0; kc < 2; kc++)
            bst[isub][kc] = *(const bf16x8*)(
                xe + (ibase + 32 * wave + 16 * isub + c) * 64 + kc * 32 + q * 8);

    f32x4 o[2][4];
#pragma unroll
    for (int g = 0; g < 2; g++)
#pragma unroll
        for (int ft = 0; ft < 4; ft++) o[g][ft] = (f32x4){0.f, 0.f, 0.f, 0.f};

    for (int jc = 0; jc < 16; jc++) {
        const int j0 = jbase + jc * 64;
        __syncthreads();
#pragma unroll
        for (int k = 0; k < 2; k++) {
            int seg = tid + k * 256; int r = seg >> 3, c8 = seg & 7;
            *(uint4*)(sJ + r * 72 + c8 * 8) = *(const uint4*)(xe + (j0 + r) * 64 + c8 * 8);
            *(uint4*)(sU + r * 72 + c8 * 8) = *(const uint4*)(uT + r * 8192 + j0 + c8 * 8);
        }
        __syncthreads();

        // S-phase: lane -> S[i=ibase+32w+16isub+c][j=j0+16jt+4q+r]
#pragma unroll
        for (int jt = 0; jt < 4; jt++) {
            bf16x8 a0 = *(const bf16x8*)(sJ + (16 * jt + c) * 72 + q * 8);
            bf16x8 a1 = *(const bf16x8*)(sJ + (16 * jt + c) * 72 + 32 + q * 8);
#pragma unroll
            for (int isub = 0; isub < 2; isub++) {
                f32x4 s = {0.f, 0.f, 0.f, 0.f};
                s = __builtin_amdgcn_mfma_f32_16x16x32_bf16(a0, bst[isub][0], s, 0, 0, 0);
                s = __builtin_amdgcn_mfma_f32_16x16x32_bf16(a1, bst[isub][1], s, 0, 0, 0);
                bf16x4 pv;
                pv[0] = (__bf16)__expf(s[0]); pv[1] = (__bf16)__expf(s[1]);
                pv[2] = (__bf16)__expf(s[2]); pv[3] = (__bf16)__expf(s[3]);
                *(bf16x4*)(sP + (32 * wave + 16 * isub + c) * 72 + 16 * jt + 4 * q) = pv;
            }
        }
        // PV-phase: sP rows 32w..32w+31 wave-private, no barrier needed
#pragma unroll
        for (int kc = 0; kc < 2; kc++) {
            bf16x8 ap0 = *(const bf16x8*)(sP + (32 * wave + c) * 72 + kc * 32 + q * 8);
            bf16x8 ap1 = *(const bf16x8*)(sP + (32 * wave + 16 + c) * 72 + kc * 32 + q * 8);
#pragma unroll
            for (int ft = 0; ft < 4; ft++) {
                bf16x8 bu = *(const bf16x8*)(sU + (16 * ft + c) * 72 + kc * 32 + q * 8);
                o[0][ft] = __builtin_amdgcn_mfma_f32_16x16x32_bf16(ap0, bu, o[0][ft], 0, 0, 0);
                o[1][ft] = __builtin_amdgcn_mfma_f32_16x16x32_bf16(ap1, bu, o[1][ft], 0, 0, 0);
            }
        }
    }
    float* dst = outp + (size_t)blockIdx.y * NF;
#pragma unroll
    for (int g = 0; g < 2; g++)
#pragma unroll
        for (int ft = 0; ft < 4; ft++)
#pragma unroll
            for (int r = 0; r < 4; r++)
                dst[(ibase + 32 * wave + 16 * g + 4 * q + r) * 64 + 16 * ft + c] =
                    o[g][ft][r];
}

// ---------------- kernel 5: combine slices -> out + fused final ---------------
// 512 blocks; thread owns 4 positions at stride 131072 (%64==0 -> fixed col).
// Last block (device-scope ticket) reduces partials and computes alpha/beta.
__global__ __launch_bounds__(256) void k_combine(
    const float* __restrict__ outp, float* __restrict__ out,
    float* __restrict__ colp, float* __restrict__ sqp, int* __restrict__ ctix,
    const float* __restrict__ wa1, const float* __restrict__ ba1,
    const float* __restrict__ wa2, const float* __restrict__ ba2,
    const float* __restrict__ wb1, const float* __restrict__ bb1,
    const float* __restrict__ wb2, const float* __restrict__ bb2)
{
    const int tid = threadIdx.x, bid = blockIdx.x;
    const int base = bid * 256 + tid;
    float col = 0.f, sq = 0.f;
#pragma unroll
    for (int k = 0; k < 4; k++) {
        int idx = base + k * 131072;
        float acc = 0.f;
#pragma unroll
        for (int s = 0; s < 8; s++) acc += outp[(size_t)s * NF + idx];
        out[idx] = acc;
        col += acc; sq += acc * acc;
    }
    __shared__ float sv[256];
    __shared__ float sw[4];
    __shared__ int isLast;
    sv[tid] = col;
#pragma unroll
    for (int m = 32; m; m >>= 1) sq += __shfl_xor(sq, m);
    if ((tid & 63) == 0) sw[tid >> 6] = sq;
    __syncthreads();
    if (tid < 64) {
        float t = sv[tid] + sv[tid + 64] + sv[tid + 128] + sv[tid + 192];
        colp[bid * 64 + tid] = t;
    }
    if (tid == 0) sqp[bid] = sw[0] + sw[1] + sw[2] + sw[3];

    // ticket: last block does the final reduction
    __threadfence();
    if (tid == 0) isLast = (atomicAdd(ctix, 1) == 511);
    __syncthreads();
    if (!isLast) return;
    __threadfence();                 // acquire: see all blocks' colp/sqp
    if (tid < 64) {
        const int f = tid;
        float colsum = 0.f;
        for (int b = 0; b < 512; b++) colsum += colp[b * 64 + f];
        float ss = colsum * colsum;
#pragma unroll
        for (int m = 32; m; m >>= 1) ss += __shfl_xor(ss, m);
        float sqt = 0.f;
#pragma unroll
        for (int k = 0; k < 8; k++) sqt += sqp[f + 64 * k];
#pragma unroll
        for (int m = 32; m; m >>= 1) sqt += __shfl_xor(sqt, m);
        if (f == 0) {
            const float invN = 1.f / 8192.f;
            float m = 2.f * invN * sqt - 2.f * invN * invN * ss;
            float h0 = tanhf(m * wa1[0] + ba1[0]);
            float h1 = tanhf(m * wa1[1] + ba1[1]);
            float a  = tanhf(h0 * wa2[0] + h1 * wa2[1] + ba2[0]);
            float g0 = tanhf(m * wb1[0] + bb1[0]);
            float g1 = tanhf(m * wb1[1] + bb1[1]);
            float b  = tanhf(g0 * wb2[0] + g1 * wb2[1] + bb2[0]);
            out[NF]     = __expf(3.f * a);
            out[NF + 1] = __expf(-3.f * b);
        }
    }
}

// ---------------- launcher ----------------------------------------------------
extern "C" void kernel_launch(void* const* d_in, const int* in_sizes, int n_in,
                              void* d_out, int out_size, void* d_ws, size_t ws_size,
                              hipStream_t stream)
{
    const float* x     = (const float*)d_in[0];
    const float* w_in1 = (const float*)d_in[1];
    const float* b_in1 = (const float*)d_in[2];
    const float* w_in2 = (const float*)d_in[3];
    const float* b_in2 = (const float*)d_in[4];
    const float* w_in3 = (const float*)d_in[5];
    const float* b_in3 = (const float*)d_in[6];
    const float* w_a1  = (const float*)d_in[7];
    const float* b_a1  = (const float*)d_in[8];
    const float* w_a2  = (const float*)d_in[9];
    const float* b_a2  = (const float*)d_in[10];
    const float* w_b1  = (const float*)d_in[11];
    const float* b_b1  = (const float*)d_in[12];
    const float* w_b2  = (const float*)d_in[13];
    const float* b_b2  = (const float*)d_in[14];

    float* out = (float*)d_out;
    char*  ws  = (char*)d_ws;
    __bf16* xe  = (__bf16*)ws;                             // 1 MB
    __bf16* uT  = (__bf16*)(ws + (1 << 20));               // 1 MB
    float*  Dp  = (float*)(ws + (2 << 20));                // 32 x 32 KB = 1 MB
    float*  colp = (float*)(ws + (3 << 20));               // 128 KB
    float*  sqp  = (float*)(ws + (3 << 20) + (128 << 10)); // 2 KB
    int*    ctix = (int*)(ws + (3 << 20) + (130 << 10));   // 4 B
    float*  outp = (float*)(ws + (4 << 20));               // 8 x 2 MB = 16 MB

    k_encode<<<NF / 256, 256, 0, stream>>>(x, w_in1, b_in1, w_in2, b_in2,
                                           w_in3, b_in3, xe, ctix);
    k_pass1<<<dim3(128, 8), 256, 0, stream>>>(xe, Dp);
    k_build_u<<<128, 256, 0, stream>>>(xe, Dp, uT);
    k_pass2<<<dim3(64, 8), 256, 0, stream>>>(xe, uT, outp);
    k_combine<<<512, 256, 0, stream>>>(outp, out, colp, sqp, ctix,
                                       w_a1, b_a1, w_a2, b_a2,
                                       w_b1, b_b1, w_b2, b_b2);
}

// Round 7
// 158.038 us; speedup vs baseline: 2.9096x; 1.3015x over previous
//
#include <hip/hip_runtime.h>
#include <cstdint>

// ---------------- types ----------------
typedef __bf16 bf16x8 __attribute__((ext_vector_type(8)));
typedef __bf16 bf16x4 __attribute__((ext_vector_type(4)));
typedef float  f32x4  __attribute__((ext_vector_type(4)));

#define N_PTS 8192
#define FDIM  64
#define NF    (N_PTS * FDIM)

__device__ __forceinline__ float ftanh(float x) {
    float e = __expf(2.f * x);
    return 1.f - 2.f / (e + 1.f);
}

// ---------------- kernel 1: per-pair encode MLP -> xe (bf16) ----------------
__global__ __launch_bounds__(256) void k_encode(
    const float* __restrict__ x,
    const float* __restrict__ w1, const float* __restrict__ b1,
    const float* __restrict__ w2, const float* __restrict__ b2,
    const float* __restrict__ w3, const float* __restrict__ b3,
    __bf16* __restrict__ xe)
{
    int idx = blockIdx.x * 256 + threadIdx.x;   // < NF
    float2 p = ((const float2*)x)[idx];
    float h1[4], h2[4];
#pragma unroll
    for (int o = 0; o < 4; o++)
        h1[o] = ftanh(p.x * w1[o] + p.y * w1[4 + o] + b1[o]);
#pragma unroll
    for (int o = 0; o < 4; o++) {
        float s = b2[o];
#pragma unroll
        for (int i = 0; i < 4; i++) s += h1[i] * w2[i * 4 + o];
        h2[o] = ftanh(s);
    }
    float s3 = b3[0];
#pragma unroll
    for (int i = 0; i < 4; i++) s3 += h2[i] * w3[i];
    xe[idx] = (__bf16)ftanh(s3);
}

// ---------------- kernel 2: D partials -----------------------------------------
// Block owns 64 j (B-frags in registers); i-rows streamed through LDS, split
// across waves. grid (128 j-tiles, 8 i-slices of 1024). 32 Dp partial slices.
__global__ __launch_bounds__(256) void k_pass1(
    const __bf16* __restrict__ xe, float* __restrict__ Dp)
{
    __shared__ __bf16 sI[128 * 72];            // padded stride 72: conflict-free
    const int tid = threadIdx.x;
    const int j0 = blockIdx.x * 64;
    const int ibase = blockIdx.y * 1024;
    const int wave = tid >> 6, lane = tid & 63, c = lane & 15, q = lane >> 4;

    bf16x8 Bf[4][2];
#pragma unroll
    for (int jt = 0; jt < 4; jt++)
#pragma unroll
        for (int kc = 0; kc < 2; kc++)
            Bf[jt][kc] = *(const bf16x8*)(xe + (j0 + 16 * jt + c) * 64 + kc * 32 + q * 8);

    float es[4] = {0.f, 0.f, 0.f, 0.f};
    for (int ic = 0; ic < 8; ic++) {
        __syncthreads();
#pragma unroll
        for (int k = 0; k < 4; k++) {
            int seg = tid + k * 256; int r = seg >> 3, c8 = seg & 7;
            *(uint4*)(sI + r * 72 + c8 * 8) =
                *(const uint4*)(xe + (ibase + ic * 128 + r) * 64 + c8 * 8);
        }
        __syncthreads();
#pragma unroll
        for (int g = 0; g < 2; g++) {
            bf16x8 a0 = *(const bf16x8*)(sI + (32 * wave + 16 * g + c) * 72 + q * 8);
            bf16x8 a1 = *(const bf16x8*)(sI + (32 * wave + 16 * g + c) * 72 + 32 + q * 8);
#pragma unroll
            for (int jt = 0; jt < 4; jt++) {
                f32x4 s = {0.f, 0.f, 0.f, 0.f};
                s = __builtin_amdgcn_mfma_f32_16x16x32_bf16(a0, Bf[jt][0], s, 0, 0, 0);
                s = __builtin_amdgcn_mfma_f32_16x16x32_bf16(a1, Bf[jt][1], s, 0, 0, 0);
                es[jt] += __expf(s.x) + __expf(s.y) + __expf(s.z) + __expf(s.w);
            }
        }
    }
#pragma unroll
    for (int jt = 0; jt < 4; jt++) {
        es[jt] += __shfl_xor(es[jt], 16);
        es[jt] += __shfl_xor(es[jt], 32);
    }
    if (q == 0) {
        float* d = Dp + (blockIdx.y * 4 + wave) * N_PTS + j0;
#pragma unroll
        for (int jt = 0; jt < 4; jt++) d[16 * jt + c] = es[jt];
    }
}

// ---------------- kernel 3: uT[f][j] = bf16(xe[j][f] / sum(Dp[:,j])) ----------
__global__ __launch_bounds__(256) void k_build_u(
    const __bf16* __restrict__ xe, const float* __restrict__ Dp,
    __bf16* __restrict__ uT)
{
    __shared__ __bf16 T[64 * 72];
    const int tid = threadIdx.x;
    const int j0 = blockIdx.x * 64;
    const int r = tid >> 2, cg = tid & 3;
    float dsum = 0.f;
#pragma unroll
    for (int s = 0; s < 32; s++) dsum += Dp[s * N_PTS + j0 + r];
    float invd = 1.0f / dsum;
    bf16x8 v0 = *(const bf16x8*)(xe + (j0 + r) * 64 + cg * 16);
    bf16x8 v1 = *(const bf16x8*)(xe + (j0 + r) * 64 + cg * 16 + 8);
#pragma unroll
    for (int e = 0; e < 8; e++) {
        T[(cg * 16 + e) * 72 + r]     = (__bf16)((float)v0[e] * invd);
        T[(cg * 16 + 8 + e) * 72 + r] = (__bf16)((float)v1[e] * invd);
    }
    __syncthreads();
    uint4 w0 = *(uint4*)((char*)T + r * 144 + cg * 32);
    uint4 w1 = *(uint4*)((char*)T + r * 144 + cg * 32 + 16);
    *(uint4*)(uT + r * 8192 + j0 + cg * 16)     = w0;
    *(uint4*)(uT + r * 8192 + j0 + cg * 16 + 8) = w1;
}

// ---------------- kernel 4: outp[slice] = exp(S_slice) @ u  (MFMA) ------------
// grid (64 i-tiles of 128, 8 j-slices of 1024); 4 waves; wave owns 32 i-rows.
// 8 outp slices (16 MB total).
__global__ __launch_bounds__(256, 2) void k_pass2(
    const __bf16* __restrict__ xe, const __bf16* __restrict__ uT,
    float* __restrict__ outp)
{
    __shared__ __bf16 sJ[64 * 72];       //  9.2 KB
    __shared__ __bf16 sU[64 * 72];       //  9.2 KB
    __shared__ __bf16 sP[128 * 72];      // 18.4 KB -> 36.9 KB total, 2 blk/CU
    const int tid = threadIdx.x;
    const int ibase = blockIdx.x * 128;
    const int jbase = blockIdx.y * 1024;
    const int wave = tid >> 6, lane = tid & 63, c = lane & 15, q = lane >> 4;

    bf16x8 bst[2][2];
#pragma unroll
    for (int isub = 0; isub < 2; isub++)
#pragma unroll
        for (int kc = 0; kc < 2; kc++)
            bst[isub][kc] = *(const bf16x8*)(
                xe + (ibase + 32 * wave + 16 * isub + c) * 64 + kc * 32 + q * 8);

    f32x4 o[2][4];
#pragma unroll
    for (int g = 0; g < 2; g++)
#pragma unroll
        for (int ft = 0; ft < 4; ft++) o[g][ft] = (f32x4){0.f, 0.f, 0.f, 0.f};

    for (int jc = 0; jc < 16; jc++) {
        const int j0 = jbase + jc * 64;
        __syncthreads();
#pragma unroll
        for (int k = 0; k < 2; k++) {
            int seg = tid + k * 256; int r = seg >> 3, c8 = seg & 7;
            *(uint4*)(sJ + r * 72 + c8 * 8) = *(const uint4*)(xe + (j0 + r) * 64 + c8 * 8);
            *(uint4*)(sU + r * 72 + c8 * 8) = *(const uint4*)(uT + r * 8192 + j0 + c8 * 8);
        }
        __syncthreads();

        // S-phase: lane -> S[i=ibase+32w+16isub+c][j=j0+16jt+4q+r]
#pragma unroll
        for (int jt = 0; jt < 4; jt++) {
            bf16x8 a0 = *(const bf16x8*)(sJ + (16 * jt + c) * 72 + q * 8);
            bf16x8 a1 = *(const bf16x8*)(sJ + (16 * jt + c) * 72 + 32 + q * 8);
#pragma unroll
            for (int isub = 0; isub < 2; isub++) {
                f32x4 s = {0.f, 0.f, 0.f, 0.f};
                s = __builtin_amdgcn_mfma_f32_16x16x32_bf16(a0, bst[isub][0], s, 0, 0, 0);
                s = __builtin_amdgcn_mfma_f32_16x16x32_bf16(a1, bst[isub][1], s, 0, 0, 0);
                bf16x4 pv;
                pv[0] = (__bf16)__expf(s[0]); pv[1] = (__bf16)__expf(s[1]);
                pv[2] = (__bf16)__expf(s[2]); pv[3] = (__bf16)__expf(s[3]);
                *(bf16x4*)(sP + (32 * wave + 16 * isub + c) * 72 + 16 * jt + 4 * q) = pv;
            }
        }
        // PV-phase: sP rows 32w..32w+31 wave-private, no barrier needed
#pragma unroll
        for (int kc = 0; kc < 2; kc++) {
            bf16x8 ap0 = *(const bf16x8*)(sP + (32 * wave + c) * 72 + kc * 32 + q * 8);
            bf16x8 ap1 = *(const bf16x8*)(sP + (32 * wave + 16 + c) * 72 + kc * 32 + q * 8);
#pragma unroll
            for (int ft = 0; ft < 4; ft++) {
                bf16x8 bu = *(const bf16x8*)(sU + (16 * ft + c) * 72 + kc * 32 + q * 8);
                o[0][ft] = __builtin_amdgcn_mfma_f32_16x16x32_bf16(ap0, bu, o[0][ft], 0, 0, 0);
                o[1][ft] = __builtin_amdgcn_mfma_f32_16x16x32_bf16(ap1, bu, o[1][ft], 0, 0, 0);
            }
        }
    }
    float* dst = outp + (size_t)blockIdx.y * NF;
#pragma unroll
    for (int g = 0; g < 2; g++)
#pragma unroll
        for (int ft = 0; ft < 4; ft++)
#pragma unroll
            for (int r = 0; r < 4; r++)
                dst[(ibase + 32 * wave + 16 * g + 4 * q + r) * 64 + 16 * ft + c] =
                    o[g][ft][r];
}

// ---------------- kernel 5: sum slices -> out, col/sq partials ----------------
// 512 blocks; thread owns 4 positions at stride 131072 (%64==0 -> fixed col).
// No atomics, no fences. k_final (separate dispatch) reduces the partials.
__global__ __launch_bounds__(256) void k_combine(
    const float* __restrict__ outp, float* __restrict__ out,
    float* __restrict__ colp, float* __restrict__ sqp)
{
    const int tid = threadIdx.x, bid = blockIdx.x;
    const int base = bid * 256 + tid;
    float col = 0.f, sq = 0.f;
#pragma unroll
    for (int k = 0; k < 4; k++) {
        int idx = base + k * 131072;
        float acc = 0.f;
#pragma unroll
        for (int s = 0; s < 8; s++) acc += outp[(size_t)s * NF + idx];
        out[idx] = acc;
        col += acc; sq += acc * acc;
    }
    __shared__ float sv[256];
    __shared__ float sw[4];
    sv[tid] = col;
#pragma unroll
    for (int m = 32; m; m >>= 1) sq += __shfl_xor(sq, m);
    if ((tid & 63) == 0) sw[tid >> 6] = sq;
    __syncthreads();
    if (tid < 64) {
        float t = sv[tid] + sv[tid + 64] + sv[tid + 128] + sv[tid + 192];
        colp[bid * 64 + tid] = t;
    }
    if (tid == 0) sqp[bid] = sw[0] + sw[1] + sw[2] + sw[3];
}

// ---------------- kernel 6: reduce partials, m -> alpha, beta -----------------
__global__ void k_final(
    const float* __restrict__ colp, const float* __restrict__ sqp,
    const float* __restrict__ wa1, const float* __restrict__ ba1,
    const float* __restrict__ wa2, const float* __restrict__ ba2,
    const float* __restrict__ wb1, const float* __restrict__ bb1,
    const float* __restrict__ wb2, const float* __restrict__ bb2,
    float* __restrict__ out_tail)
{
    const int f = threadIdx.x;   // 64 threads, 1 block
    float colsum = 0.f;
    for (int b = 0; b < 512; b++) colsum += colp[b * 64 + f];
    float ss = colsum * colsum;
#pragma unroll
    for (int m = 32; m; m >>= 1) ss += __shfl_xor(ss, m);
    float sq = 0.f;
#pragma unroll
    for (int k = 0; k < 8; k++) sq += sqp[f + 64 * k];
#pragma unroll
    for (int m = 32; m; m >>= 1) sq += __shfl_xor(sq, m);
    if (f == 0) {
        const float invN = 1.f / 8192.f;
        float m = 2.f * invN * sq - 2.f * invN * invN * ss;
        float h0 = tanhf(m * wa1[0] + ba1[0]);
        float h1 = tanhf(m * wa1[1] + ba1[1]);
        float a  = tanhf(h0 * wa2[0] + h1 * wa2[1] + ba2[0]);
        float g0 = tanhf(m * wb1[0] + bb1[0]);
        float g1 = tanhf(m * wb1[1] + bb1[1]);
        float b  = tanhf(g0 * wb2[0] + g1 * wb2[1] + bb2[0]);
        out_tail[0] = __expf(3.f * a);
        out_tail[1] = __expf(-3.f * b);
    }
}

// ---------------- launcher ----------------------------------------------------
extern "C" void kernel_launch(void* const* d_in, const int* in_sizes, int n_in,
                              void* d_out, int out_size, void* d_ws, size_t ws_size,
                              hipStream_t stream)
{
    const float* x     = (const float*)d_in[0];
    const float* w_in1 = (const float*)d_in[1];
    const float* b_in1 = (const float*)d_in[2];
    const float* w_in2 = (const float*)d_in[3];
    const float* b_in2 = (const float*)d_in[4];
    const float* w_in3 = (const float*)d_in[5];
    const float* b_in3 = (const float*)d_in[6];
    const float* w_a1  = (const float*)d_in[7];
    const float* b_a1  = (const float*)d_in[8];
    const float* w_a2  = (const float*)d_in[9];
    const float* b_a2  = (const float*)d_in[10];
    const float* w_b1  = (const float*)d_in[11];
    const float* b_b1  = (const float*)d_in[12];
    const float* w_b2  = (const float*)d_in[13];
    const float* b_b2  = (const float*)d_in[14];

    float* out = (float*)d_out;
    char*  ws  = (char*)d_ws;
    __bf16* xe  = (__bf16*)ws;                             // 1 MB
    __bf16* uT  = (__bf16*)(ws + (1 << 20));               // 1 MB
    float*  Dp  = (float*)(ws + (2 << 20));                // 32 x 32 KB = 1 MB
    float*  colp = (float*)(ws + (3 << 20));               // 128 KB
    float*  sqp  = (float*)(ws + (3 << 20) + (128 << 10)); // 2 KB
    float*  outp = (float*)(ws + (4 << 20));               // 8 x 2 MB = 16 MB

    k_encode<<<NF / 256, 256, 0, stream>>>(x, w_in1, b_in1, w_in2, b_in2,
                                           w_in3, b_in3, xe);
    k_pass1<<<dim3(128, 8), 256, 0, stream>>>(xe, Dp);
    k_build_u<<<128, 256, 0, stream>>>(xe, Dp, uT);
    k_pass2<<<dim3(64, 8), 256, 0, stream>>>(xe, uT, outp);
    k_combine<<<512, 256, 0, stream>>>(outp, out, colp, sqp);
    k_final<<<1, 64, 0, stream>>>(colp, sqp, w_a1, b_a1, w_a2, b_a2,
                                  w_b1, b_b1, w_b2, b_b2, out + NF);
}